// Round 31
// baseline (156.206 us; speedup 1.0000x reference)
//
#include <hip/hip_runtime.h>
#include <hip/hip_bf16.h>

// Sheaf CNN on the fixed ring graph (offsets ±1..4 mod 4096, degree 8).
// SINGLE fused dispatch (256 x 1024), built from proven-fast pieces:
//   - weights f32 in LDS (R24 staging), ef for 32 ext nodes
//   - GEMV: R30's 4-nodes-per-wave pattern, 8 waves (halo recompute)
//   - A/B/H written from regs into overlay over dead Wa (R25 machinery)
//   - K2 phases 2-4 verbatim on local LDS (d_ws A/B/G round-trip GONE)
//   - last-block atomic finalize (R21/R25-proven), Wc1/Wc2 overlay Wb/Wh
// Theory: ~35us of the 52us 3-dispatch pipeline is per-dispatch fixed
// cost; fused removes 2 dispatches + inter-kernel staging.
// Fallbacks byte-preserved: ws>=32KB -> R17 128-block halo kernel +
// finalize; else R8 single-block.

#define NN    4096
#define CHK   32            // R17 fallback: chunk nodes
#define EXT   48            // R17 fallback: chunk + 2*8 halo
#define PEXT  40            // R17 fallback: chunk + 2*4 halo
#define NGRID 128           // R17 fallback grid
#define WS_R17 (NGRID * 64u * 4u)

#define NBLKF 256           // fused grid (16 owned nodes/block)
#define WS_FUSED (4096u + NBLKF * 64u * 4u)

struct Smem {
    float As[EXT][64];
    float Bs[EXT][64];
    float Gs[EXT][64];
    float Hs[16][64];
    float ps[PEXT][8][2];
    float dinvs[PEXT][2];
    float facs[PEXT][2];
    float red[1024];
    float pooled[64];
    float hid[128];
};

struct SmemFin {
    float Wc1s[64][128];
    float Wc2s[128][8];
    float red[256];
    float pooled[64];
    float hid[128];
};

// Fused LDS: 142.4 KB static. Wa hosts As/Bs/Gs overlay after GEMV;
// Wb hosts Wc1s, Wh hosts Wc2s in the last-block finalize.
struct SmemF {
    float Wa[128][64];    // 32KB  -> overlay: As[24][64]|Bs[32][64]|Gs[32][64]
    float Wb[128][64];    // 32KB  -> overlay: Wc1s[64][128]
    float Wh[128][64];    // 32KB  -> overlay: Wc2s[128][8]
    float W2s[64][64];    // 16KB
    float efs[32][128];   // 16KB (ext nodes base-8..base+23)
    float Hs[32][64];     // 8KB
    float ps[24][8][2];
    float dinvs[24][2];
    float facs[24][2];
    float red[1024];
    float pooled[64];
    float hid[128];
};

template <bool F32>
static __device__ __forceinline__ float ldv(const void* p, int i) {
    if constexpr (F32) return ((const float*)p)[i];
    else return __bfloat162float(((const __hip_bfloat16*)p)[i]);
}

static __device__ __forceinline__ float ldr(const void* p, int i, bool f32) {
    if (f32) return ((const float*)p)[i];
    return __bfloat162float(((const __hip_bfloat16*)p)[i]);
}

static __device__ __forceinline__ float blo(unsigned u) {
    return __uint_as_float(u << 16);
}
static __device__ __forceinline__ float bhi(unsigned u) {
    return __uint_as_float(u & 0xFFFF0000u);
}

// ---------- R8/R17-proven halo body (fallback paths) ----------
template <bool F32>
static __device__ void body(Smem& sm,
    const void* ef, const void* We, const void* be, const void* M1w,
    const void* M1b, const void* M2w, const void* M2b, const void* W1,
    const void* W2, const void* Wc1, const void* bc1, const void* Wc2,
    const void* bc2, void* out)
{
    const int t = threadIdx.x;
    const int c = t & 63;
    const int w = t >> 6;
    const int a = (t >> 6) & 1;
    const int ms = t >> 7;

    const float m1b_c = ldv<F32>(M1b, c);
    const float m2w0  = ldv<F32>(M2w, c * 2 + 0);
    const float m2w1  = ldv<F32>(M2w, c * 2 + 1);
    const float m2b0  = ldv<F32>(M2b, 0);
    const float m2b1  = ldv<F32>(M2b, 1);
    const float cs0 = ldv<F32>(W1, 0) + ldv<F32>(W1, 2);
    const float cs1 = ldv<F32>(W1, 1) + ldv<F32>(W1, 3);
    const float bec = ldv<F32>(be, c);

    float accY = 0.f;

    for (int ch = blockIdx.x; ch < NN / CHK; ch += gridDim.x) {
        const int c0 = ch * CHK;
        for (int pp = 0; pp < EXT / 16; ++pp) {
            const int q  = pp * 16 + w;
            const int gi = (c0 - 8 + q) & (NN - 1);
            float aA = 0.f, aB = 0.f, aH = bec;
            #pragma unroll 2
            for (int k = 0; k < 128; ++k) {
                const float ev = ldv<F32>(ef, gi * 128 + k);
                aA += ev * ldv<F32>(M1w, k * 64 + c);
                aB += ev * ldv<F32>(M1w, 8192 + k * 64 + c);
                aH += ev * ldv<F32>(We, k * 64 + c);
            }
            sm.As[q][c] = aA;
            sm.Bs[q][c] = aB;
            sm.Hs[w][c] = fmaxf(aH, 0.f);
            __syncthreads();
            float aG = 0.f;
            #pragma unroll 2
            for (int k = 0; k < 64; ++k)
                aG += sm.Hs[w][k] * ldv<F32>(W2, k * 64 + c);
            sm.Gs[q][c] = aG;
            __syncthreads();
        }
        for (int pi = w; pi < PEXT * 8; pi += 16) {
            const int r  = pi >> 3;
            const int tt = pi & 7;
            const int off = (tt < 4) ? (tt - 4) : (tt - 3);
            const float h = fmaxf(sm.As[r + 4][c] + sm.Bs[r + 4 + off][c] + m1b_c, 0.f);
            float q0 = h * m2w0, q1 = h * m2w1;
            #pragma unroll
            for (int d2 = 32; d2; d2 >>= 1) {
                q0 += __shfl_xor(q0, d2);
                q1 += __shfl_xor(q1, d2);
            }
            if (c == 0) {
                sm.ps[r][tt][0] = q0 + m2b0;
                sm.ps[r][tt][1] = q1 + m2b1;
            }
        }
        __syncthreads();
        if (t < PEXT * 2) {
            const int r = t >> 1, aa = t & 1;
            float s = 0.f;
            #pragma unroll
            for (int tt = 0; tt < 8; ++tt) { const float p = sm.ps[r][tt][aa]; s += p * p; }
            const float dv = 1.f / sqrtf(fmaxf(s + 1e-5f, 1e-6f));
            sm.dinvs[r][aa] = dv;
            sm.facs[r][aa]  = 1.f - dv * dv * s;
        }
        __syncthreads();
        const float csa = a ? cs1 : cs0;
        #pragma unroll
        for (int it = 0; it < 4; ++it) {
            const int m = it * 8 + ms;
            const int r = m + 4;
            const int g = m + 8;
            const float di = sm.dinvs[r][a];
            float v = sm.facs[r][a] * sm.Gs[g][c];
            #pragma unroll
            for (int tt = 0; tt < 8; ++tt) {
                const int off = (tt < 4) ? (tt - 4) : (tt - 3);
                v += di * sm.ps[r + off][7 - tt][a] * sm.ps[r][tt][a]
                        * sm.dinvs[r + off][a] * sm.Gs[g + off][c];
            }
            const float x = csa * v;
            accY += (x > 0.f) ? x : expm1f(x);
        }
        __syncthreads();
    }

    sm.red[t] = accY;
    __syncthreads();

    if (gridDim.x > 1) {
        if (t < 64) {
            float s = 0.f;
            #pragma unroll
            for (int g2 = 0; g2 < 16; ++g2) s += sm.red[(g2 << 6) + t];
            ((float*)out)[blockIdx.x * 64 + t] = s;
        }
        return;
    }

    if (t < 64) {
        float s = 0.f;
        #pragma unroll
        for (int g2 = 0; g2 < 16; ++g2) s += sm.red[(g2 << 6) + t];
        sm.pooled[t] = s * (1.f / 8192.f);
    }
    __syncthreads();
    if (t < 128) {
        float acc = ldv<F32>(bc1, t);
        #pragma unroll 8
        for (int k = 0; k < 64; ++k) acc += sm.pooled[k] * ldv<F32>(Wc1, k * 128 + t);
        sm.hid[t] = fmaxf(acc, 0.f);
    }
    __syncthreads();
    if (t < 8) {
        float acc = ldv<F32>(bc2, t);
        #pragma unroll 8
        for (int k = 0; k < 128; ++k) acc += sm.hid[k] * ldv<F32>(Wc2, k * 8 + t);
        if constexpr (F32) ((float*)out)[t] = acc;
        else ((__hip_bfloat16*)out)[t] = __float2bfloat16(acc);
    }
}

// ---------- fused body ----------
template <bool F32>
static __device__ void fusedbody(SmemF& sm, int& lastFlag,
    const void* ef, const void* We, const void* be, const void* M1w,
    const void* M1b, const void* M2w, const void* M2b, const void* W1,
    const void* W2, const void* Wc1, const void* bc1, const void* Wc2,
    const void* bc2, unsigned int* counter, float* partials, void* out)
{
    const int t = threadIdx.x, c = t & 63, w = t >> 6;
    const int base = blockIdx.x * 16;
    float* As = &sm.Wa[0][0];            // [24][64] overlay (ext 4..27)
    float* Bs = As + 24 * 64;            // [32][64]
    float* Gs = Bs + 32 * 64;            // [32][64]

    float rA[4], rB[4], rH[4];

    if constexpr (!F32) {
        // ---- stage weights (R24-proven) + ef ext rows ----
        const unsigned* M1u = (const unsigned*)M1w;
        const unsigned* Weu = (const unsigned*)We;
        const unsigned* W2u = (const unsigned*)W2;
        const unsigned* efu = (const unsigned*)ef;
        #pragma unroll
        for (int rep = 0; rep < 4; ++rep) {
            const int j = rep * 1024 + t;               // j < 4096
            const int k = j >> 5, c2 = (j & 31) * 2;
            const unsigned a = M1u[j];
            sm.Wa[k][c2] = blo(a);  sm.Wa[k][c2 + 1] = bhi(a);
            const unsigned b = M1u[4096 + j];
            sm.Wb[k][c2] = blo(b);  sm.Wb[k][c2 + 1] = bhi(b);
            const unsigned h = Weu[j];
            sm.Wh[k][c2] = blo(h);  sm.Wh[k][c2 + 1] = bhi(h);
        }
        #pragma unroll
        for (int rep = 0; rep < 2; ++rep) {
            const int j = rep * 1024 + t;               // j < 2048
            const int k = j >> 5, c2 = (j & 31) * 2;
            const unsigned v = W2u[j];
            sm.W2s[k][c2] = blo(v);  sm.W2s[k][c2 + 1] = bhi(v);
        }
        #pragma unroll
        for (int rep = 0; rep < 2; ++rep) {
            const int j = rep * 1024 + t;               // j < 2048
            const int row = j >> 6, kk = (j & 63) * 2;
            const unsigned u = efu[(((base - 8 + row) & (NN - 1)) << 6) + (j & 63)];
            sm.efs[row][kk] = blo(u);  sm.efs[row][kk + 1] = bhi(u);
        }
        __syncthreads();

        // ---- GEMV: waves 0..7, wave w owns ext nodes 4w..4w+3 (R30) ----
        if (w < 8) {
            const int n0 = w * 4;
            const float bec = ldv<false>(be, c);
            #pragma unroll
            for (int i = 0; i < 4; ++i) { rA[i] = 0.f; rB[i] = 0.f; rH[i] = bec; }
            #pragma unroll 4
            for (int k = 0; k < 128; ++k) {
                const float wa = sm.Wa[k][c];
                const float wb = sm.Wb[k][c];
                const float wh = sm.Wh[k][c];
                #pragma unroll
                for (int i = 0; i < 4; ++i) {
                    const float e = sm.efs[n0 + i][k];
                    rA[i] = fmaf(e, wa, rA[i]);
                    rB[i] = fmaf(e, wb, rB[i]);
                    rH[i] = fmaf(e, wh, rH[i]);
                }
            }
        }
        __syncthreads();                   // Wa/Wb reads complete

        // ---- write A/B/H into overlay ----
        if (w < 8) {
            const int n0 = w * 4;
            #pragma unroll
            for (int i = 0; i < 4; ++i) {
                const int q = n0 + i;
                if (q >= 4 && q < 28) As[(q - 4) * 64 + c] = rA[i];
                Bs[q * 64 + c] = rB[i];
                sm.Hs[q][c] = fmaxf(rH[i], 0.f);
            }
        }
        __syncthreads();

        // ---- G: 16 waves, wave w -> ext nodes 2w, 2w+1 ----
        {
            const int q0 = 2 * w, q1 = 2 * w + 1;
            float g0 = 0.f, g1 = 0.f;
            #pragma unroll 8
            for (int k = 0; k < 64; ++k) {
                const float wv = sm.W2s[k][c];
                g0 = fmaf(sm.Hs[q0][k], wv, g0);
                g1 = fmaf(sm.Hs[q1][k], wv, g1);
            }
            Gs[q0 * 64 + c] = g0;
            Gs[q1 * 64 + c] = g1;
        }
        __syncthreads();
    } else {
        // ---- f32 path (never triggers): direct global loops ----
        const float* eff = (const float*)ef;
        const float* M1f = (const float*)M1w;
        const float* Wef = (const float*)We;
        for (int o = t; o < 32 * 192; o += 1024) {
            const int n = o / 192, j = o % 192;       // ext node n, out col j
            const int gi = (base - 8 + n) & (NN - 1);
            float s = (j >= 128) ? ((const float*)be)[j - 128] : 0.f;
            for (int k = 0; k < 128; ++k) {
                const float e = eff[gi * 128 + k];
                const float wv = (j < 64) ? M1f[k * 64 + j]
                               : (j < 128) ? M1f[8192 + k * 64 + (j - 64)]
                               : Wef[k * 64 + (j - 128)];
                s += e * wv;
            }
            if (j < 64) { if (n >= 4 && n < 28) As[(n - 4) * 64 + j] = s; }
            else if (j < 128) Bs[n * 64 + (j - 64)] = s;
            else sm.Hs[n][j - 128] = fmaxf(s, 0.f);
        }
        __syncthreads();
        const float* W2f = (const float*)W2;
        for (int o = t; o < 32 * 64; o += 1024) {
            const int n = o >> 6, cc = o & 63;
            float s = 0.f;
            for (int k = 0; k < 64; ++k) s += sm.Hs[n][k] * W2f[k * 64 + cc];
            Gs[n * 64 + cc] = s;
        }
        __syncthreads();
    }

    const float m1b_c = ldv<F32>(M1b, c);
    const float m2w0  = ldv<F32>(M2w, c * 2 + 0);
    const float m2w1  = ldv<F32>(M2w, c * 2 + 1);
    const float m2b0  = ldv<F32>(M2b, 0);
    const float m2b1  = ldv<F32>(M2b, 1);
    const float cs0 = ldv<F32>(W1, 0) + ldv<F32>(W1, 2);
    const float cs1 = ldv<F32>(W1, 1) + ldv<F32>(W1, 3);

    // ---- phase 2: p(r,tt), r in [0,24) (node base-4+r = ext r+4) ----
    for (int pi = w; pi < 24 * 8; pi += 16) {
        const int r  = pi >> 3;
        const int tt = pi & 7;
        const int off = (tt < 4) ? (tt - 4) : (tt - 3);
        const float h = fmaxf(As[r * 64 + c] + Bs[(r + 4 + off) * 64 + c] + m1b_c, 0.f);
        float q0 = h * m2w0, q1 = h * m2w1;
        #pragma unroll
        for (int d2 = 32; d2; d2 >>= 1) {
            q0 += __shfl_xor(q0, d2);
            q1 += __shfl_xor(q1, d2);
        }
        if (c == 0) {
            sm.ps[r][tt][0] = q0 + m2b0;
            sm.ps[r][tt][1] = q1 + m2b1;
        }
    }
    __syncthreads();

    // ---- phase 3 ----
    if (t < 48) {
        const int r = t >> 1, aa = t & 1;
        float s = 0.f;
        #pragma unroll
        for (int tt = 0; tt < 8; ++tt) { const float p = sm.ps[r][tt][aa]; s += p * p; }
        const float dv = 1.f / sqrtf(fmaxf(s + 1e-5f, 1e-6f));
        sm.dinvs[r][aa] = dv;
        sm.facs[r][aa]  = 1.f - dv * dv * s;
    }
    __syncthreads();

    // ---- phase 4: 16 owned nodes (ext 8..23) ----
    float accY = 0.f;
    #pragma unroll
    for (int it = 0; it < 2; ++it) {
        const int m = it * 8 + (t >> 7);
        const int a = (t >> 6) & 1;
        const int r = m + 4;
        const int g = m + 8;
        const float csa = a ? cs1 : cs0;
        const float di = sm.dinvs[r][a];
        float v = sm.facs[r][a] * Gs[g * 64 + c];
        #pragma unroll
        for (int tt = 0; tt < 8; ++tt) {
            const int off = (tt < 4) ? (tt - 4) : (tt - 3);
            v += di * sm.ps[r + off][7 - tt][a] * sm.ps[r][tt][a]
                    * sm.dinvs[r + off][a] * Gs[(g + off) * 64 + c];
        }
        const float x = csa * v;
        accY += (x > 0.f) ? x : expm1f(x);
    }

    // ---- block partial -> global; last-block finalize ----
    sm.red[t] = accY;
    __syncthreads();
    if (t < 64) {
        float s = 0.f;
        #pragma unroll
        for (int g2 = 0; g2 < 16; ++g2) s += sm.red[(g2 << 6) + t];
        partials[blockIdx.x * 64 + t] = s;
    }
    __threadfence();
    __syncthreads();
    if (t == 0) {
        const unsigned old = atomicAdd(counter, 1u);
        lastFlag = (old == (unsigned)(gridDim.x - 1)) ? 1 : 0;
    }
    __syncthreads();
    if (!lastFlag) return;
    __threadfence();
    if (t == 0) *counter = 0;

    // finalize: Wc1s over Wb, Wc2s over Wh
    float* Wc1s = &sm.Wb[0][0];            // [64][128]
    float* Wc2s = &sm.Wh[0][0];            // [128][8]
    if constexpr (F32) {
        for (int idx = t; idx < 64 * 128; idx += 1024)
            Wc1s[idx] = ((const float*)Wc1)[idx];
        if (t < 128 * 8) Wc2s[t] = ((const float*)Wc2)[t];
    } else {
        #pragma unroll
        for (int rep = 0; rep < 4; ++rep) {
            const int j = rep * 1024 + t;               // j < 4096
            const unsigned u = ((const unsigned*)Wc1)[j];
            Wc1s[j * 2] = blo(u);  Wc1s[j * 2 + 1] = bhi(u);
        }
        if (t < 512) {
            const unsigned u = ((const unsigned*)Wc2)[t];
            Wc2s[t * 2] = blo(u);  Wc2s[t * 2 + 1] = bhi(u);
        }
    }
    {
        float s = 0.f;
        for (int b = w; b < NBLKF; b += 16) s += partials[b * 64 + c];
        sm.red[w * 64 + c] = s;
    }
    __syncthreads();
    if (t < 64) {
        float tot = 0.f;
        #pragma unroll
        for (int g2 = 0; g2 < 16; ++g2) tot += sm.red[g2 * 64 + t];
        sm.pooled[t] = tot * (1.0f / 8192.0f);
    }
    __syncthreads();
    if (t < 128) {
        float acc = ldv<F32>(bc1, t);
        #pragma unroll 8
        for (int k = 0; k < 64; ++k) acc = fmaf(sm.pooled[k], Wc1s[k * 128 + t], acc);
        sm.hid[t] = fmaxf(acc, 0.f);
    }
    __syncthreads();
    if (t < 8) {
        float acc = ldv<F32>(bc2, t);
        #pragma unroll 8
        for (int k = 0; k < 128; ++k) acc = fmaf(sm.hid[k], Wc2s[k * 8 + t], acc);
        if constexpr (F32) ((float*)out)[t] = acc;
        else ((__hip_bfloat16*)out)[t] = __float2bfloat16(acc);
    }
}

__global__ __launch_bounds__(1024) void sheaf_fused(
    const void* ef, const void* We, const void* be, const void* M1w,
    const void* M1b, const void* M2w, const void* M2b, const void* W1,
    const void* W2, const void* Wc1, const void* bc1, const void* Wc2,
    const void* bc2, unsigned int* counter, float* partials, void* out)
{
    __shared__ SmemF sm;
    __shared__ int flag;
    __shared__ int lastFlag;
    const int t = threadIdx.x;
    if (t == 0) flag = 0;
    __syncthreads();
    {
        const __hip_bfloat16* efh = (const __hip_bfloat16*)ef;
        bool big = false;
        #pragma unroll
        for (int k = 0; k < 8; ++k) {
            const float v = __bfloat162float(efh[t * 8 + k]);
            big |= !(fabsf(v) < 1e4f);
        }
        if (big) atomicOr(&flag, 1);
    }
    __syncthreads();
    if (flag)
        fusedbody<true >(sm, lastFlag, ef, We, be, M1w, M1b, M2w, M2b, W1, W2,
                         Wc1, bc1, Wc2, bc2, counter, partials, out);
    else
        fusedbody<false>(sm, lastFlag, ef, We, be, M1w, M1b, M2w, M2b, W1, W2,
                         Wc1, bc1, Wc2, bc2, counter, partials, out);
}

// ---------- finalize (R17 fallback path) ----------
template <bool F32>
static __device__ void finbody(SmemFin& sm,
    const void* Wc1, const void* bc1, const void* Wc2, const void* bc2,
    const float* partials, int nparts, void* out)
{
    const int t = threadIdx.x;

    if constexpr (F32) {
        for (int idx = t; idx < 64 * 128; idx += 256)
            sm.Wc1s[idx >> 7][idx & 127] = ((const float*)Wc1)[idx];
        for (int idx = t; idx < 128 * 8; idx += 256)
            sm.Wc2s[idx >> 3][idx & 7] = ((const float*)Wc2)[idx];
    } else {
        for (int j = t; j < 4096; j += 256) {
            const int k = j >> 6, c2 = (j & 63) * 2;
            const unsigned u = ((const unsigned*)Wc1)[j];
            sm.Wc1s[k][c2] = blo(u);  sm.Wc1s[k][c2 + 1] = bhi(u);
        }
        for (int j = t; j < 512; j += 256) {
            const int k = j >> 2, c2 = (j & 3) * 2;
            const unsigned u = ((const unsigned*)Wc2)[j];
            sm.Wc2s[k][c2] = blo(u);  sm.Wc2s[k][c2 + 1] = bhi(u);
        }
    }

    const int h = t & 63, g = t >> 6;
    float s = 0.f;
    for (int b = g; b < nparts; b += 4) s += partials[b * 64 + h];
    sm.red[t] = s;
    __syncthreads();
    if (t < 64)
        sm.pooled[t] = (sm.red[t] + sm.red[t + 64] + sm.red[t + 128] + sm.red[t + 192])
                       * (1.f / 8192.f);
    __syncthreads();
    if (t < 128) {
        float acc = ldv<F32>(bc1, t);
        #pragma unroll 8
        for (int k = 0; k < 64; ++k) acc = fmaf(sm.pooled[k], sm.Wc1s[k][t], acc);
        sm.hid[t] = fmaxf(acc, 0.f);
    }
    __syncthreads();
    if (t < 8) {
        float acc = ldv<F32>(bc2, t);
        #pragma unroll 8
        for (int k = 0; k < 128; ++k) acc = fmaf(sm.hid[k], sm.Wc2s[k][t], acc);
        if constexpr (F32) ((float*)out)[t] = acc;
        else ((__hip_bfloat16*)out)[t] = __float2bfloat16(acc);
    }
}

__global__ __launch_bounds__(256) void sheaf_finalize(
    const void* ef, const void* Wc1, const void* bc1, const void* Wc2,
    const void* bc2, const float* partials, int nparts, void* out)
{
    __shared__ SmemFin sm;
    __shared__ int flag;
    const int t = threadIdx.x;
    if (t == 0) flag = 0;
    __syncthreads();
    {
        const __hip_bfloat16* efh = (const __hip_bfloat16*)ef;
        bool big = false;
        #pragma unroll
        for (int k = 0; k < 8; ++k) {
            const float v = __bfloat162float(efh[t * 8 + k]);
            big |= !(fabsf(v) < 1e4f);
        }
        if (big) atomicOr(&flag, 1);
    }
    __syncthreads();
    if (flag) finbody<true >(sm, Wc1, bc1, Wc2, bc2, partials, nparts, out);
    else      finbody<false>(sm, Wc1, bc1, Wc2, bc2, partials, nparts, out);
}

__global__ __launch_bounds__(1024) void SheafConvolutionalNetwork_81698867905240_kernel(
    const void* ef, const void* We, const void* be, const void* M1w,
    const void* M1b, const void* M2w, const void* M2b, const void* W1,
    const void* W2, const void* Wc1, const void* bc1, const void* Wc2,
    const void* bc2, void* out)
{
    __shared__ Smem sm;
    __shared__ int flag;
    const int t = threadIdx.x;
    if (t == 0) flag = 0;
    __syncthreads();
    {
        const __hip_bfloat16* efh = (const __hip_bfloat16*)ef;
        bool big = false;
        #pragma unroll
        for (int k = 0; k < 8; ++k) {
            const float v = __bfloat162float(efh[t * 8 + k]);
            big |= !(fabsf(v) < 1e4f);
        }
        if (big) atomicOr(&flag, 1);
    }
    __syncthreads();
    if (flag)
        body<true >(sm, ef, We, be, M1w, M1b, M2w, M2b, W1, W2, Wc1, bc1, Wc2, bc2, out);
    else
        body<false>(sm, ef, We, be, M1w, M1b, M2w, M2b, W1, W2, Wc1, bc1, Wc2, bc2, out);
}

extern "C" void kernel_launch(void* const* d_in, const int* in_sizes, int n_in,
                              void* d_out, int out_size, void* d_ws, size_t ws_size,
                              hipStream_t stream)
{
    (void)in_sizes; (void)n_in; (void)out_size;
    (void)hipGetLastError();   // clear stale error

    if (d_ws != nullptr && ws_size >= (size_t)WS_FUSED) {
        unsigned int* counter = (unsigned int*)d_ws;
        float* partials = (float*)((char*)d_ws + 4096);
        (void)hipMemsetAsync(d_ws, 0, 4096, stream);   // in-graph counter reset
        sheaf_fused<<<dim3(NBLKF), dim3(1024), 0, stream>>>(
            d_in[0], d_in[1], d_in[2], d_in[3], d_in[4], d_in[5], d_in[6],
            d_in[7], d_in[8], d_in[9], d_in[10], d_in[11], d_in[12],
            counter, partials, d_out);
    } else if (d_ws != nullptr && ws_size >= (size_t)WS_R17) {
        SheafConvolutionalNetwork_81698867905240_kernel<<<dim3(NGRID), dim3(1024), 0, stream>>>(
            d_in[0], d_in[1], d_in[2], d_in[3], d_in[4], d_in[5], d_in[6],
            d_in[7], d_in[8], d_in[9], d_in[10], d_in[11], d_in[12], d_ws);
        sheaf_finalize<<<dim3(1), dim3(256), 0, stream>>>(
            d_in[0], d_in[9], d_in[10], d_in[11], d_in[12],
            (const float*)d_ws, NGRID, d_out);
    } else {
        SheafConvolutionalNetwork_81698867905240_kernel<<<dim3(1), dim3(1024), 0, stream>>>(
            d_in[0], d_in[1], d_in[2], d_in[3], d_in[4], d_in[5], d_in[6],
            d_in[7], d_in[8], d_in[9], d_in[10], d_in[11], d_in[12], d_out);
    }

    if (hipGetLastError() != hipSuccess)
        (void)hipMemsetAsync(d_out, 0x41, 16, stream);
}

// Round 32
// 52.086 us; speedup vs baseline: 2.9990x; 2.9990x over previous
//
#include <hip/hip_runtime.h>
#include <hip/hip_bf16.h>

// Sheaf CNN on the fixed ring graph (offsets ±1..4 mod 4096, degree 8).
// 3-dispatch pipeline (R24/R29-proven base, 53.6us), 4-nodes-per-wave K1:
//   K1: weights f32 in LDS (proven staging); GEMV by waves 0..3, each
//       owning 4 nodes: per k = 4 b32 broadcasts + 3 b32 weight reads
//       (2-way, free) feeding 12 FMAs -> LDS wave-ops 8192 -> 3584 /CU.
//       Same primitives, same per-node accumulation order => bit-exact.
//   K2: phases 2-4 per 16-node chunk (byte-identical)
//   K3: finalize with Wc1/Wc2 LDS-staged (byte-identical)
// Closed: MFMA-K1 (R26), bf16-packed K1 (R27), b128-bcast K1 (R28),
// fused single-dispatch (R21/R25/R31 -- 105-156us + replay pathology).
// Fallbacks byte-preserved: ws>=32KB -> R17 128-block halo kernel +
// finalize; else R8 single-block.

#define NN    4096
#define CHK   32            // R17 fallback: chunk nodes
#define EXT   48            // R17 fallback: chunk + 2*8 halo
#define PEXT  40            // R17 fallback: chunk + 2*4 halo
#define NGRID 128           // R17 fallback grid
#define WS_R17 (NGRID * 64u * 4u)

#define NBLK2 256           // pipeline grid (16 nodes/block)
#define PEXT2 24            // 16 + 2*4
#define WS_PIPE ((3u * NN * 64u + NBLK2 * 64u) * 4u)

struct Smem {
    float As[EXT][64];
    float Bs[EXT][64];
    float Gs[EXT][64];
    float Hs[16][64];
    float ps[PEXT][8][2];
    float dinvs[PEXT][2];
    float facs[PEXT][2];
    float red[1024];
    float pooled[64];
    float hid[128];
};

struct SmemK1 {
    float Wa[128][64];    // M1w rows 0..127   (32KB)
    float Wb[128][64];    // M1w rows 128..255 (32KB)
    float Wh[128][64];    // We                (32KB)
    float W2s[64][64];    // W2                (16KB)
    float efs[16][128];   // ef rows           (8KB)
    float Hs[16][64];     // relu(ef@We+be)    (4KB)
};

struct SmemK2 {
    float As[PEXT2][64];
    float Bs[32][64];
    float Gs[32][64];
    float ps[PEXT2][8][2];
    float dinvs[PEXT2][2];
    float facs[PEXT2][2];
    float red[1024];
};

struct SmemFin {
    float Wc1s[64][128];  // 32KB
    float Wc2s[128][8];   // 4KB
    float red[256];
    float pooled[64];
    float hid[128];
};

template <bool F32>
static __device__ __forceinline__ float ldv(const void* p, int i) {
    if constexpr (F32) return ((const float*)p)[i];
    else return __bfloat162float(((const __hip_bfloat16*)p)[i]);
}

static __device__ __forceinline__ float ldr(const void* p, int i, bool f32) {
    if (f32) return ((const float*)p)[i];
    return __bfloat162float(((const __hip_bfloat16*)p)[i]);
}

static __device__ __forceinline__ float blo(unsigned u) {
    return __uint_as_float(u << 16);
}
static __device__ __forceinline__ float bhi(unsigned u) {
    return __uint_as_float(u & 0xFFFF0000u);
}

// ---------- R8/R17-proven halo body (fallback paths) ----------
template <bool F32>
static __device__ void body(Smem& sm,
    const void* ef, const void* We, const void* be, const void* M1w,
    const void* M1b, const void* M2w, const void* M2b, const void* W1,
    const void* W2, const void* Wc1, const void* bc1, const void* Wc2,
    const void* bc2, void* out)
{
    const int t = threadIdx.x;
    const int c = t & 63;
    const int w = t >> 6;
    const int a = (t >> 6) & 1;
    const int ms = t >> 7;

    const float m1b_c = ldv<F32>(M1b, c);
    const float m2w0  = ldv<F32>(M2w, c * 2 + 0);
    const float m2w1  = ldv<F32>(M2w, c * 2 + 1);
    const float m2b0  = ldv<F32>(M2b, 0);
    const float m2b1  = ldv<F32>(M2b, 1);
    const float cs0 = ldv<F32>(W1, 0) + ldv<F32>(W1, 2);
    const float cs1 = ldv<F32>(W1, 1) + ldv<F32>(W1, 3);
    const float bec = ldv<F32>(be, c);

    float accY = 0.f;

    for (int ch = blockIdx.x; ch < NN / CHK; ch += gridDim.x) {
        const int c0 = ch * CHK;
        for (int pp = 0; pp < EXT / 16; ++pp) {
            const int q  = pp * 16 + w;
            const int gi = (c0 - 8 + q) & (NN - 1);
            float aA = 0.f, aB = 0.f, aH = bec;
            #pragma unroll 2
            for (int k = 0; k < 128; ++k) {
                const float ev = ldv<F32>(ef, gi * 128 + k);
                aA += ev * ldv<F32>(M1w, k * 64 + c);
                aB += ev * ldv<F32>(M1w, 8192 + k * 64 + c);
                aH += ev * ldv<F32>(We, k * 64 + c);
            }
            sm.As[q][c] = aA;
            sm.Bs[q][c] = aB;
            sm.Hs[w][c] = fmaxf(aH, 0.f);
            __syncthreads();
            float aG = 0.f;
            #pragma unroll 2
            for (int k = 0; k < 64; ++k)
                aG += sm.Hs[w][k] * ldv<F32>(W2, k * 64 + c);
            sm.Gs[q][c] = aG;
            __syncthreads();
        }
        for (int pi = w; pi < PEXT * 8; pi += 16) {
            const int r  = pi >> 3;
            const int tt = pi & 7;
            const int off = (tt < 4) ? (tt - 4) : (tt - 3);
            const float h = fmaxf(sm.As[r + 4][c] + sm.Bs[r + 4 + off][c] + m1b_c, 0.f);
            float q0 = h * m2w0, q1 = h * m2w1;
            #pragma unroll
            for (int d2 = 32; d2; d2 >>= 1) {
                q0 += __shfl_xor(q0, d2);
                q1 += __shfl_xor(q1, d2);
            }
            if (c == 0) {
                sm.ps[r][tt][0] = q0 + m2b0;
                sm.ps[r][tt][1] = q1 + m2b1;
            }
        }
        __syncthreads();
        if (t < PEXT * 2) {
            const int r = t >> 1, aa = t & 1;
            float s = 0.f;
            #pragma unroll
            for (int tt = 0; tt < 8; ++tt) { const float p = sm.ps[r][tt][aa]; s += p * p; }
            const float dv = 1.f / sqrtf(fmaxf(s + 1e-5f, 1e-6f));
            sm.dinvs[r][aa] = dv;
            sm.facs[r][aa]  = 1.f - dv * dv * s;
        }
        __syncthreads();
        const float csa = a ? cs1 : cs0;
        #pragma unroll
        for (int it = 0; it < 4; ++it) {
            const int m = it * 8 + ms;
            const int r = m + 4;
            const int g = m + 8;
            const float di = sm.dinvs[r][a];
            float v = sm.facs[r][a] * sm.Gs[g][c];
            #pragma unroll
            for (int tt = 0; tt < 8; ++tt) {
                const int off = (tt < 4) ? (tt - 4) : (tt - 3);
                v += di * sm.ps[r + off][7 - tt][a] * sm.ps[r][tt][a]
                        * sm.dinvs[r + off][a] * sm.Gs[g + off][c];
            }
            const float x = csa * v;
            accY += (x > 0.f) ? x : expm1f(x);
        }
        __syncthreads();
    }

    sm.red[t] = accY;
    __syncthreads();

    if (gridDim.x > 1) {
        if (t < 64) {
            float s = 0.f;
            #pragma unroll
            for (int g2 = 0; g2 < 16; ++g2) s += sm.red[(g2 << 6) + t];
            ((float*)out)[blockIdx.x * 64 + t] = s;
        }
        return;
    }

    if (t < 64) {
        float s = 0.f;
        #pragma unroll
        for (int g2 = 0; g2 < 16; ++g2) s += sm.red[(g2 << 6) + t];
        sm.pooled[t] = s * (1.f / 8192.f);
    }
    __syncthreads();
    if (t < 128) {
        float acc = ldv<F32>(bc1, t);
        #pragma unroll 8
        for (int k = 0; k < 64; ++k) acc += sm.pooled[k] * ldv<F32>(Wc1, k * 128 + t);
        sm.hid[t] = fmaxf(acc, 0.f);
    }
    __syncthreads();
    if (t < 8) {
        float acc = ldv<F32>(bc2, t);
        #pragma unroll 8
        for (int k = 0; k < 128; ++k) acc += sm.hid[k] * ldv<F32>(Wc2, k * 8 + t);
        if constexpr (F32) ((float*)out)[t] = acc;
        else ((__hip_bfloat16*)out)[t] = __float2bfloat16(acc);
    }
}

// ---------- K1: node GEMVs, weights in LDS, 4 nodes/wave ----------
template <bool F32>
static __device__ void k1body(SmemK1& sm,
    const void* ef, const void* We, const void* be, const void* M1w,
    const void* W2, float* A, float* B, float* G)
{
    const int t = threadIdx.x, c = t & 63, w = t >> 6;
    const int base = blockIdx.x * 16;

    // ---- stage weights into LDS (R24-proven, all 1024 threads) ----
    if constexpr (F32) {
        for (int idx = t; idx < 128 * 64; idx += 1024) {
            const int k = idx >> 6, cc = idx & 63;
            sm.Wa[k][cc] = ((const float*)M1w)[idx];
            sm.Wb[k][cc] = ((const float*)M1w)[8192 + idx];
            sm.Wh[k][cc] = ((const float*)We)[idx];
        }
        for (int idx = t; idx < 64 * 64; idx += 1024)
            sm.W2s[idx >> 6][idx & 63] = ((const float*)W2)[idx];
        for (int idx = t; idx < 16 * 128; idx += 1024)
            sm.efs[idx >> 7][idx & 127] = ((const float*)ef)[(base << 7) + idx];
    } else {
        for (int j = t; j < 4096; j += 1024) {          // 128 rows x 32 words
            const int k = j >> 5, c2 = (j & 31) * 2;
            const unsigned a = ((const unsigned*)M1w)[j];
            sm.Wa[k][c2] = blo(a);  sm.Wa[k][c2 + 1] = bhi(a);
            const unsigned b = ((const unsigned*)M1w)[4096 + j];
            sm.Wb[k][c2] = blo(b);  sm.Wb[k][c2 + 1] = bhi(b);
            const unsigned h = ((const unsigned*)We)[j];
            sm.Wh[k][c2] = blo(h);  sm.Wh[k][c2 + 1] = bhi(h);
        }
        for (int j = t; j < 2048; j += 1024) {          // 64 rows x 32 words
            const int k = j >> 5, c2 = (j & 31) * 2;
            const unsigned v = ((const unsigned*)W2)[j];
            sm.W2s[k][c2] = blo(v);  sm.W2s[k][c2 + 1] = bhi(v);
        }
        for (int j = t; j < 16 * 64; j += 1024) {       // ef: 16 rows x 64 words
            const int n = j >> 6, kk = (j & 63) * 2;
            const unsigned u = ((const unsigned*)ef)[(base << 6) + j];
            sm.efs[n][kk] = blo(u);  sm.efs[n][kk + 1] = bhi(u);
        }
    }
    __syncthreads();

    // ---- GEMV: waves 0..3, wave w owns nodes 4w..4w+3 ----
    // per k: 3 weight reads (2-way bank, free) + 4 broadcasts -> 12 FMAs
    if (w < 4) {
        const int n0 = w * 4;
        const float bec = ldv<F32>(be, c);
        float aA0 = 0.f, aA1 = 0.f, aA2 = 0.f, aA3 = 0.f;
        float aB0 = 0.f, aB1 = 0.f, aB2 = 0.f, aB3 = 0.f;
        float aH0 = bec, aH1 = bec, aH2 = bec, aH3 = bec;
        #pragma unroll 4
        for (int k = 0; k < 128; ++k) {
            const float wa = sm.Wa[k][c];
            const float wb = sm.Wb[k][c];
            const float wh = sm.Wh[k][c];
            const float e0 = sm.efs[n0 + 0][k];
            const float e1 = sm.efs[n0 + 1][k];
            const float e2 = sm.efs[n0 + 2][k];
            const float e3 = sm.efs[n0 + 3][k];
            aA0 = fmaf(e0, wa, aA0);  aB0 = fmaf(e0, wb, aB0);  aH0 = fmaf(e0, wh, aH0);
            aA1 = fmaf(e1, wa, aA1);  aB1 = fmaf(e1, wb, aB1);  aH1 = fmaf(e1, wh, aH1);
            aA2 = fmaf(e2, wa, aA2);  aB2 = fmaf(e2, wb, aB2);  aH2 = fmaf(e2, wh, aH2);
            aA3 = fmaf(e3, wa, aA3);  aB3 = fmaf(e3, wb, aB3);  aH3 = fmaf(e3, wh, aH3);
        }
        A[((base + n0 + 0) << 6) + c] = aA0;
        A[((base + n0 + 1) << 6) + c] = aA1;
        A[((base + n0 + 2) << 6) + c] = aA2;
        A[((base + n0 + 3) << 6) + c] = aA3;
        B[((base + n0 + 0) << 6) + c] = aB0;
        B[((base + n0 + 1) << 6) + c] = aB1;
        B[((base + n0 + 2) << 6) + c] = aB2;
        B[((base + n0 + 3) << 6) + c] = aB3;
        sm.Hs[n0 + 0][c] = fmaxf(aH0, 0.f);
        sm.Hs[n0 + 1][c] = fmaxf(aH1, 0.f);
        sm.Hs[n0 + 2][c] = fmaxf(aH2, 0.f);
        sm.Hs[n0 + 3][c] = fmaxf(aH3, 0.f);
    }
    __syncthreads();

    // ---- G = relu(H) @ W2: all 16 waves, one node each (R24 pattern) ----
    float aG = 0.f;
    #pragma unroll 8
    for (int k = 0; k < 64; ++k)
        aG = fmaf(sm.Hs[w][k], sm.W2s[k][c], aG);
    G[((base + w) << 6) + c] = aG;
}

__global__ __launch_bounds__(1024) void sheaf_k1(
    const void* ef, const void* We, const void* be, const void* M1w,
    const void* W2, float* A, float* B, float* G)
{
    __shared__ SmemK1 sm;
    __shared__ int flag;
    const int t = threadIdx.x;
    if (t == 0) flag = 0;
    __syncthreads();
    {
        const __hip_bfloat16* efh = (const __hip_bfloat16*)ef;
        bool big = false;
        #pragma unroll
        for (int k = 0; k < 8; ++k) {
            const float v = __bfloat162float(efh[t * 8 + k]);
            big |= !(fabsf(v) < 1e4f);
        }
        if (big) atomicOr(&flag, 1);
    }
    __syncthreads();
    if (flag) k1body<true >(sm, ef, We, be, M1w, W2, A, B, G);
    else      k1body<false>(sm, ef, We, be, M1w, W2, A, B, G);
}

// ---------- K2: sheaf stencil phases 2-4 (R24-proven) ----------
template <bool F32>
static __device__ void k2body(SmemK2& sm,
    const void* M1b, const void* M2w, const void* M2b, const void* W1,
    const float* A, const float* B, const float* G, float* partials)
{
    const int t = threadIdx.x, c = t & 63, w = t >> 6;
    const int base = blockIdx.x * 16;

    for (int idx = t; idx < PEXT2 * 64; idx += 1024) {
        const int r = idx >> 6, cc = idx & 63;
        sm.As[r][cc] = A[(((base - 4 + r) & (NN - 1)) << 6) + cc];
    }
    for (int idx = t; idx < 32 * 64; idx += 1024) {
        const int r = idx >> 6, cc = idx & 63;
        const int gi = ((base - 8 + r) & (NN - 1)) << 6;
        sm.Bs[r][cc] = B[gi + cc];
        sm.Gs[r][cc] = G[gi + cc];
    }
    __syncthreads();

    const float m1b_c = ldv<F32>(M1b, c);
    const float m2w0  = ldv<F32>(M2w, c * 2 + 0);
    const float m2w1  = ldv<F32>(M2w, c * 2 + 1);
    const float m2b0  = ldv<F32>(M2b, 0);
    const float m2b1  = ldv<F32>(M2b, 1);
    const float cs0 = ldv<F32>(W1, 0) + ldv<F32>(W1, 2);
    const float cs1 = ldv<F32>(W1, 1) + ldv<F32>(W1, 3);

    for (int pi = w; pi < PEXT2 * 8; pi += 16) {
        const int r  = pi >> 3;
        const int tt = pi & 7;
        const int off = (tt < 4) ? (tt - 4) : (tt - 3);
        const float h = fmaxf(sm.As[r][c] + sm.Bs[r + 4 + off][c] + m1b_c, 0.f);
        float q0 = h * m2w0, q1 = h * m2w1;
        #pragma unroll
        for (int d2 = 32; d2; d2 >>= 1) {
            q0 += __shfl_xor(q0, d2);
            q1 += __shfl_xor(q1, d2);
        }
        if (c == 0) {
            sm.ps[r][tt][0] = q0 + m2b0;
            sm.ps[r][tt][1] = q1 + m2b1;
        }
    }
    __syncthreads();

    if (t < PEXT2 * 2) {
        const int r = t >> 1, aa = t & 1;
        float s = 0.f;
        #pragma unroll
        for (int tt = 0; tt < 8; ++tt) { const float p = sm.ps[r][tt][aa]; s += p * p; }
        const float dv = 1.f / sqrtf(fmaxf(s + 1e-5f, 1e-6f));
        sm.dinvs[r][aa] = dv;
        sm.facs[r][aa]  = 1.f - dv * dv * s;
    }
    __syncthreads();

    float accY = 0.f;
    #pragma unroll
    for (int it = 0; it < 2; ++it) {
        const int m = it * 8 + (t >> 7);
        const int a = (t >> 6) & 1;
        const int r = m + 4;
        const int g = m + 8;
        const float csa = a ? cs1 : cs0;
        const float di = sm.dinvs[r][a];
        float v = sm.facs[r][a] * sm.Gs[g][c];
        #pragma unroll
        for (int tt = 0; tt < 8; ++tt) {
            const int off = (tt < 4) ? (tt - 4) : (tt - 3);
            v += di * sm.ps[r + off][7 - tt][a] * sm.ps[r][tt][a]
                    * sm.dinvs[r + off][a] * sm.Gs[g + off][c];
        }
        const float x = csa * v;
        accY += (x > 0.f) ? x : expm1f(x);
    }

    sm.red[t] = accY;
    __syncthreads();
    if (t < 64) {
        float s = 0.f;
        #pragma unroll
        for (int g2 = 0; g2 < 16; ++g2) s += sm.red[(g2 << 6) + t];
        partials[blockIdx.x * 64 + t] = s;
    }
}

__global__ __launch_bounds__(1024) void sheaf_k2(
    const void* ef, const void* M1b, const void* M2w, const void* M2b,
    const void* W1, const float* A, const float* B, const float* G,
    float* partials)
{
    __shared__ SmemK2 sm;
    __shared__ int flag;
    const int t = threadIdx.x;
    if (t == 0) flag = 0;
    __syncthreads();
    {
        const __hip_bfloat16* efh = (const __hip_bfloat16*)ef;
        bool big = false;
        #pragma unroll
        for (int k = 0; k < 8; ++k) {
            const float v = __bfloat162float(efh[t * 8 + k]);
            big |= !(fabsf(v) < 1e4f);
        }
        if (big) atomicOr(&flag, 1);
    }
    __syncthreads();
    if (flag) k2body<true >(sm, M1b, M2w, M2b, W1, A, B, G, partials);
    else      k2body<false>(sm, M1b, M2w, M2b, W1, A, B, G, partials);
}

// ---------- finalize: Wc1/Wc2 LDS-staged reduce + classifier ----------
template <bool F32>
static __device__ void finbody(SmemFin& sm,
    const void* Wc1, const void* bc1, const void* Wc2, const void* bc2,
    const float* partials, int nparts, void* out)
{
    const int t = threadIdx.x;

    if constexpr (F32) {
        for (int idx = t; idx < 64 * 128; idx += 256)
            sm.Wc1s[idx >> 7][idx & 127] = ((const float*)Wc1)[idx];
        for (int idx = t; idx < 128 * 8; idx += 256)
            sm.Wc2s[idx >> 3][idx & 7] = ((const float*)Wc2)[idx];
    } else {
        for (int j = t; j < 4096; j += 256) {           // 64 rows x 64 words
            const int k = j >> 6, c2 = (j & 63) * 2;
            const unsigned u = ((const unsigned*)Wc1)[j];
            sm.Wc1s[k][c2] = blo(u);  sm.Wc1s[k][c2 + 1] = bhi(u);
        }
        for (int j = t; j < 512; j += 256) {            // 128 rows x 4 words
            const int k = j >> 2, c2 = (j & 3) * 2;
            const unsigned u = ((const unsigned*)Wc2)[j];
            sm.Wc2s[k][c2] = blo(u);  sm.Wc2s[k][c2 + 1] = bhi(u);
        }
    }

    const int h = t & 63, g = t >> 6;
    float s = 0.f;
    for (int b = g; b < nparts; b += 4) s += partials[b * 64 + h];
    sm.red[t] = s;
    __syncthreads();
    if (t < 64)
        sm.pooled[t] = (sm.red[t] + sm.red[t + 64] + sm.red[t + 128] + sm.red[t + 192])
                       * (1.f / 8192.f);
    __syncthreads();
    if (t < 128) {
        float acc = ldv<F32>(bc1, t);
        #pragma unroll 8
        for (int k = 0; k < 64; ++k) acc = fmaf(sm.pooled[k], sm.Wc1s[k][t], acc);
        sm.hid[t] = fmaxf(acc, 0.f);
    }
    __syncthreads();
    if (t < 8) {
        float acc = ldv<F32>(bc2, t);
        #pragma unroll 8
        for (int k = 0; k < 128; ++k) acc = fmaf(sm.hid[k], sm.Wc2s[k][t], acc);
        if constexpr (F32) ((float*)out)[t] = acc;
        else ((__hip_bfloat16*)out)[t] = __float2bfloat16(acc);
    }
}

__global__ __launch_bounds__(256) void sheaf_finalize(
    const void* ef, const void* Wc1, const void* bc1, const void* Wc2,
    const void* bc2, const float* partials, int nparts, void* out)
{
    __shared__ SmemFin sm;
    __shared__ int flag;
    const int t = threadIdx.x;
    if (t == 0) flag = 0;
    __syncthreads();
    {
        const __hip_bfloat16* efh = (const __hip_bfloat16*)ef;
        bool big = false;
        #pragma unroll
        for (int k = 0; k < 8; ++k) {
            const float v = __bfloat162float(efh[t * 8 + k]);
            big |= !(fabsf(v) < 1e4f);
        }
        if (big) atomicOr(&flag, 1);
    }
    __syncthreads();
    if (flag) finbody<true >(sm, Wc1, bc1, Wc2, bc2, partials, nparts, out);
    else      finbody<false>(sm, Wc1, bc1, Wc2, bc2, partials, nparts, out);
}

__global__ __launch_bounds__(1024) void SheafConvolutionalNetwork_81698867905240_kernel(
    const void* ef, const void* We, const void* be, const void* M1w,
    const void* M1b, const void* M2w, const void* M2b, const void* W1,
    const void* W2, const void* Wc1, const void* bc1, const void* Wc2,
    const void* bc2, void* out)
{
    __shared__ Smem sm;
    __shared__ int flag;
    const int t = threadIdx.x;
    if (t == 0) flag = 0;
    __syncthreads();
    {
        const __hip_bfloat16* efh = (const __hip_bfloat16*)ef;
        bool big = false;
        #pragma unroll
        for (int k = 0; k < 8; ++k) {
            const float v = __bfloat162float(efh[t * 8 + k]);
            big |= !(fabsf(v) < 1e4f);
        }
        if (big) atomicOr(&flag, 1);
    }
    __syncthreads();
    if (flag)
        body<true >(sm, ef, We, be, M1w, M1b, M2w, M2b, W1, W2, Wc1, bc1, Wc2, bc2, out);
    else
        body<false>(sm, ef, We, be, M1w, M1b, M2w, M2b, W1, W2, Wc1, bc1, Wc2, bc2, out);
}

extern "C" void kernel_launch(void* const* d_in, const int* in_sizes, int n_in,
                              void* d_out, int out_size, void* d_ws, size_t ws_size,
                              hipStream_t stream)
{
    (void)in_sizes; (void)n_in; (void)out_size;
    (void)hipGetLastError();   // clear stale error

    if (d_ws != nullptr && ws_size >= (size_t)WS_PIPE) {
        float* A = (float*)d_ws;
        float* B = A + NN * 64;
        float* G = B + NN * 64;
        float* partials = G + NN * 64;
        sheaf_k1<<<dim3(NBLK2), dim3(1024), 0, stream>>>(
            d_in[0], d_in[1], d_in[2], d_in[3], d_in[8], A, B, G);
        sheaf_k2<<<dim3(NBLK2), dim3(1024), 0, stream>>>(
            d_in[0], d_in[4], d_in[5], d_in[6], d_in[7], A, B, G, partials);
        sheaf_finalize<<<dim3(1), dim3(256), 0, stream>>>(
            d_in[0], d_in[9], d_in[10], d_in[11], d_in[12],
            partials, NBLK2, d_out);
    } else if (d_ws != nullptr && ws_size >= (size_t)WS_R17) {
        // R17-proven fallback: 128-block halo kernel + finalize
        SheafConvolutionalNetwork_81698867905240_kernel<<<dim3(NGRID), dim3(1024), 0, stream>>>(
            d_in[0], d_in[1], d_in[2], d_in[3], d_in[4], d_in[5], d_in[6],
            d_in[7], d_in[8], d_in[9], d_in[10], d_in[11], d_in[12], d_ws);
        sheaf_finalize<<<dim3(1), dim3(256), 0, stream>>>(
            d_in[0], d_in[9], d_in[10], d_in[11], d_in[12],
            (const float*)d_ws, NGRID, d_out);
    } else {
        // R8-proven fallback: single block direct to d_out
        SheafConvolutionalNetwork_81698867905240_kernel<<<dim3(1), dim3(1024), 0, stream>>>(
            d_in[0], d_in[1], d_in[2], d_in[3], d_in[4], d_in[5], d_in[6],
            d_in[7], d_in[8], d_in[9], d_in[10], d_in[11], d_in[12], d_out);
    }

    // Explicit launch-error marker (~12.06 in both dtypes).
    if (hipGetLastError() != hipSuccess)
        (void)hipMemsetAsync(d_out, 0x41, 16, stream);
}